// Round 5
// baseline (1310.556 us; speedup 1.0000x reference)
//
#include <hip/hip_runtime.h>

// LightGCN 3-layer propagation — R5 (= R4 with compile fix): nt-streaming
// epilogue + 8-lane prop.
//
// R4 failed to compile: __builtin_nontemporal_* needs native vector types,
// not HIP_vector_type<float,4>. Use ext_vector_type(4) for those accesses.
//
// Theory unchanged: (a) 8 threads/node (2 float4 each) -> 2x gathers in
// flight, half the redundant srw reads; (b) non-temporal stores for layer-3 +
// mean outputs and nt loads for x0..x2 (pure streaming) so the layer-2 gather
// set stays L3-resident during the fused prop3.

static constexpr int NUSERS = 500000;
static constexpr int NITEMS = 200000;
static constexpr int NNODES = 700000;   // NUSERS + NITEMS
static constexpr int NE     = 5000000;
static constexpr int SCAN_B = 1024;
static constexpr int NSB    = (NNODES + SCAN_B - 1) / SCAN_B;   // 684 scan blocks

typedef float f4 __attribute__((ext_vector_type(4)));   // native vec for nt ops

// --- int degree histogram over col -------------------------------------------
__global__ void k_hist(const int* __restrict__ col, int* __restrict__ deg) {
    int e = blockIdx.x * blockDim.x + threadIdx.x;
    if (e < NE) atomicAdd(&deg[col[e]], 1);
}

// --- per-block exclusive scan (Hillis-Steele in LDS) --------------------------
__global__ void k_scan1(const int* __restrict__ deg, int* __restrict__ offs,
                        int* __restrict__ bsums) {
    __shared__ int s[SCAN_B];
    int t = threadIdx.x;
    int i = blockIdx.x * SCAN_B + t;
    int v = (i < NNODES) ? deg[i] : 0;
    s[t] = v;
    __syncthreads();
    for (int off = 1; off < SCAN_B; off <<= 1) {
        int add = (t >= off) ? s[t - off] : 0;
        __syncthreads();
        s[t] += add;
        __syncthreads();
    }
    if (i < NNODES) offs[i] = s[t] - v;          // exclusive
    if (t == SCAN_B - 1) bsums[blockIdx.x] = s[t];
}

// --- scan the 684 block sums (single block) -----------------------------------
__global__ void k_scan2(int* __restrict__ bsums) {
    __shared__ int s[SCAN_B];
    int t = threadIdx.x;
    int v = (t < NSB) ? bsums[t] : 0;
    s[t] = v;
    __syncthreads();
    for (int off = 1; off < SCAN_B; off <<= 1) {
        int add = (t >= off) ? s[t - off] : 0;
        __syncthreads();
        s[t] += add;
        __syncthreads();
    }
    if (t < NSB) bsums[t] = s[t] - v;            // exclusive block offsets
}

// --- finalize offsets; init cursor copy; dinv ----------------------------------
__global__ void k_scan3(int* __restrict__ offs, const int* __restrict__ bsums,
                        int* __restrict__ cursor, const int* __restrict__ deg,
                        float* __restrict__ dinv) {
    int i = blockIdx.x * blockDim.x + threadIdx.x;
    if (i < NNODES) {
        int o = offs[i] + bsums[i >> 10];
        offs[i]   = o;
        cursor[i] = o;
        int d = deg[i];
        dinv[i] = (d > 0) ? rsqrtf((float)d) : 0.0f;
    }
    if (i == 0) offs[NNODES] = NE;
}

// --- scatter edges into col-sorted order: (row, w) packed 8B ------------------
__global__ void k_scatter(const int* __restrict__ row, const int* __restrict__ col,
                          const float* __restrict__ dinv, int* __restrict__ cursor,
                          int2* __restrict__ srw) {
    int e = blockIdx.x * blockDim.x + threadIdx.x;
    if (e >= NE) return;
    int r = row[e], c = col[e];
    int pos = atomicAdd(&cursor[c], 1);
    float w = dinv[r] * dinv[c];
    srw[pos] = make_int2(r, __float_as_int(w));
}

// --- init all_emb layer 0 (layers 1..3 fully overwritten by k_prop) ----------
__global__ void k_init(const float4* __restrict__ user, const float4* __restrict__ item,
                       float4* __restrict__ all_emb) {
    int tid = blockIdx.x * blockDim.x + threadIdx.x;
    if (tid >= NNODES * 16) return;
    int node = tid >> 4;
    int lane = tid & 15;
    float4 v = (node < NUSERS) ? user[node * 16 + lane]
                               : item[(node - NUSERS) * 16 + lane];
    all_emb[(size_t)node * 64 + lane] = v;
}

// --- propagate layer l: 8 threads/node, 2 float4 per thread ------------------
// FUSE_OUT (layer 3): nt-streaming epilogue writes layer 3 + 4-layer mean.
template <int L, bool FUSE_OUT>
__global__ void k_prop(const int* __restrict__ offs, const int2* __restrict__ srw,
                       float4* __restrict__ all_emb,
                       float* __restrict__ out_users, float* __restrict__ out_items) {
    int tid = blockIdx.x * blockDim.x + threadIdx.x;
    if (tid >= NNODES * 8) return;
    int n    = tid >> 3;
    int lane = tid & 7;                    // handles float4 slots lane*2, lane*2+1
    int b = offs[n], e = offs[n + 1];
    float4 accA = make_float4(0.f, 0.f, 0.f, 0.f);
    float4 accB = make_float4(0.f, 0.f, 0.f, 0.f);
    const float4* src = all_emb + (L - 1) * 16 + lane * 2;

#define EDGE_FMA(rw)                                                          \
    {                                                                         \
        float w = __int_as_float((rw).y);                                     \
        const float4* s_ = src + (size_t)(rw).x * 64;                         \
        float4 va = s_[0], vb = s_[1];                                        \
        accA.x += w * va.x; accA.y += w * va.y;                               \
        accA.z += w * va.z; accA.w += w * va.w;                               \
        accB.x += w * vb.x; accB.y += w * vb.y;                               \
        accB.z += w * vb.z; accB.w += w * vb.w;                               \
    }

    int k = b;
    for (; k + 4 <= e; k += 4) {
        int2 rw0 = srw[k + 0];
        int2 rw1 = srw[k + 1];
        int2 rw2 = srw[k + 2];
        int2 rw3 = srw[k + 3];
        EDGE_FMA(rw0); EDGE_FMA(rw1); EDGE_FMA(rw2); EDGE_FMA(rw3);
    }
    for (; k < e; ++k) {
        int2 rw = srw[k];
        EDGE_FMA(rw);
    }
#undef EDGE_FMA

    float4* dst = all_emb + (size_t)n * 64 + L * 16 + lane * 2;
    if (!FUSE_OUT) {
        dst[0] = accA;
        dst[1] = accB;
    } else {
        const f4* p = reinterpret_cast<const f4*>(all_emb + (size_t)n * 64 + lane * 2);
        f4 x0a = __builtin_nontemporal_load(p + 0);
        f4 x0b = __builtin_nontemporal_load(p + 1);
        f4 x1a = __builtin_nontemporal_load(p + 16);
        f4 x1b = __builtin_nontemporal_load(p + 17);
        f4 x2a = __builtin_nontemporal_load(p + 32);
        f4 x2b = __builtin_nontemporal_load(p + 33);
        f4 aA = {accA.x, accA.y, accA.z, accA.w};
        f4 aB = {accB.x, accB.y, accB.z, accB.w};
        f4* dstn = reinterpret_cast<f4*>(dst);
        __builtin_nontemporal_store(aA, dstn + 0);
        __builtin_nontemporal_store(aB, dstn + 1);
        f4 ma = (x0a + x1a + x2a + aA) * 0.25f;
        f4 mb = (x0b + x1b + x2b + aB) * 0.25f;
        if (n < NUSERS) {
            f4* ou = reinterpret_cast<f4*>(out_users + (size_t)n * 64 + lane * 8);
            __builtin_nontemporal_store(ma, ou + 0);
            __builtin_nontemporal_store(mb, ou + 1);
        }
        if (n >= NITEMS) {
            f4* oi = reinterpret_cast<f4*>(out_items + (size_t)(n - NITEMS) * 64 + lane * 8);
            __builtin_nontemporal_store(ma, oi + 0);
            __builtin_nontemporal_store(mb, oi + 1);
        }
    }
}

extern "C" void kernel_launch(void* const* d_in, const int* in_sizes, int n_in,
                              void* d_out, int out_size, void* d_ws, size_t ws_size,
                              hipStream_t stream) {
    const float* user  = (const float*)d_in[0];
    const float* item  = (const float*)d_in[1];
    const int*   edges = (const int*)d_in[2];
    const int*   row = edges;            // edge_index[0]
    const int*   col = edges + NE;       // edge_index[1]

    float* out       = (float*)d_out;
    float* out_users = out;
    float* out_items = out + (size_t)NUSERS * 64;
    float* all_emb   = out + (size_t)NUSERS * 64 * 2;   // [700000][4][64]

    // workspace carve (~51 MB)
    char* ws = (char*)d_ws;
    int*   deg    = (int*)ws;                         ws += (size_t)NNODES * 4;
    int*   offs   = (int*)ws;                         ws += (size_t)(NNODES + 1) * 4;
    int*   cursor = (int*)ws;                         ws += (size_t)NNODES * 4;
    int*   bsums  = (int*)ws;                         ws += (size_t)SCAN_B * 4;
    float* dinv   = (float*)ws;                       ws += (size_t)NNODES * 4;
    int2*  srw    = (int2*)ws;                        ws += (size_t)NE * 8;

    const int B = 256;
    const int prop_grid = (NNODES * 8 + B - 1) / B;

    hipMemsetAsync(deg, 0, (size_t)NNODES * sizeof(int), stream);
    k_hist <<<(NE + B - 1) / B, B, 0, stream>>>(col, deg);
    k_scan1<<<NSB, SCAN_B, 0, stream>>>(deg, offs, bsums);
    k_scan2<<<1, SCAN_B, 0, stream>>>(bsums);
    k_scan3<<<(NNODES + B - 1) / B, B, 0, stream>>>(offs, bsums, cursor, deg, dinv);
    k_scatter<<<(NE + B - 1) / B, B, 0, stream>>>(row, col, dinv, cursor, srw);
    k_init <<<(NNODES * 16 + B - 1) / B, B, 0, stream>>>(
        (const float4*)user, (const float4*)item, (float4*)all_emb);

    k_prop<1, false><<<prop_grid, B, 0, stream>>>(offs, srw, (float4*)all_emb,
                                                  nullptr, nullptr);
    k_prop<2, false><<<prop_grid, B, 0, stream>>>(offs, srw, (float4*)all_emb,
                                                  nullptr, nullptr);
    k_prop<3, true> <<<prop_grid, B, 0, stream>>>(offs, srw, (float4*)all_emb,
                                                  out_users, out_items);
}